// Round 12
// baseline (742.636 us; speedup 1.0000x reference)
//
#include <hip/hip_runtime.h>
#include <hip/hip_fp16.h>
#include <math.h>
#include <float.h>

#define NLOC 20000
#define TT   24
#define NP   12      // timestep pairs
#define INDIM 18
#define HH   32
#define PWN  15
#define PSTR 32      // uint stride between pooled keys (128B)

typedef unsigned short u16;

__device__ __forceinline__ unsigned int fkey(float f) {
    unsigned int b = __float_as_uint(f);
    return b ^ ((unsigned int)((int)b >> 31) | 0x80000000u);
}
__device__ __forceinline__ float funkey(unsigned int u) {
    return (u & 0x80000000u) ? __uint_as_float(u ^ 0x80000000u) : __uint_as_float(~u);
}

// Balanced pair->XCD map: XCD x owns pair x (all nblk blocks) plus half of pair
// 8+(x>>1) -> 1.5 pairs per XCD. Flat grid = 8*(nblk+half); blockIdx%8 ~ XCD.
__device__ __forceinline__ bool decode_bal(int nblk, int half, int swz, int qadd,
                                           int& q, int& blk) {
    if (swz) {
        int F = blockIdx.x;
        int x = F & 7;
        int g = F >> 3;
        if (g < nblk) { q = x; blk = g; return true; }
        int h = g - nblk;                    // [0, half)
        q = 8 + (x >> 1);
        blk = (x & 1) * half + h;
        return blk < nblk;
    }
    q = qadd + blockIdx.y;
    blk = blockIdx.x;
    return true;
}

// ---------------- CSR build ----------------
__global__ void count_kernel(const int* __restrict__ dst, int* __restrict__ cnt, int E) {
    int e = blockIdx.x * blockDim.x + threadIdx.x;
    if (e < E) atomicAdd(&cnt[dst[e]], 1);
}

__global__ void scan_kernel(const int* __restrict__ cnt, int* __restrict__ row_ptr, int n) {
    __shared__ int sums[1024];
    const int CH = 20;
    int tid = threadIdx.x;
    int base = tid * CH;
    int local[CH];
    int s = 0;
    #pragma unroll
    for (int i = 0; i < CH; ++i) {
        int idx = base + i;
        int v = (idx < n) ? cnt[idx] : 0;
        local[i] = s;
        s += v;
    }
    sums[tid] = s;
    __syncthreads();
    for (int o = 1; o < 1024; o <<= 1) {
        int v = (tid >= o) ? sums[tid - o] : 0;
        __syncthreads();
        sums[tid] += v;
        __syncthreads();
    }
    int pre = (tid > 0) ? sums[tid - 1] : 0;
    #pragma unroll
    for (int i = 0; i < CH; ++i) {
        int idx = base + i;
        if (idx < n) row_ptr[idx] = pre + local[i];
    }
    if (tid == 1023) row_ptr[n] = sums[1023];
}

__global__ void scatter_kernel(const int* __restrict__ src, const int* __restrict__ dst,
                               const int* __restrict__ row_ptr, int* __restrict__ fill,
                               u16* __restrict__ csr_src, int E) {
    int e = blockIdx.x * blockDim.x + threadIdx.x;
    if (e < E) {
        int d = dst[e];
        int pos = row_ptr[d] + atomicAdd(&fill[d], 1);
        csr_src[pos] = (u16)src[e];
    }
}

// ---------------- layer-1 node transform for a t-pair: z2 interleaved half2(t0,t1)
__global__ void node1_kernel(const float* __restrict__ dyn,
                             const float* __restrict__ W, const float* __restrict__ b,
                             const float* __restrict__ aW, const float* __restrict__ ab,
                             __half2* __restrict__ z2, float2* __restrict__ es2,
                             float2* __restrict__ ed2, int nblk, int half, int swz, int qadd) {
    __shared__ float sW[HH * INDIM];
    __shared__ float sb[HH];
    __shared__ float saW[2 * HH];
    __shared__ float sab;
    int q, blk;
    bool alive = decode_bal(nblk, half, swz, qadd, q, blk);
    int slice = swz ? q : blockIdx.y;
    int tid = threadIdx.x;
    for (int i = tid; i < HH * INDIM; i += blockDim.x) sW[i] = W[i];
    if (tid < HH) sb[tid] = b[tid];
    if (tid < 2 * HH) saW[tid] = aW[tid];
    if (tid == 0) sab = ab[0];
    __syncthreads();
    if (!alive) return;
    int n = blk * blockDim.x + tid;
    if (n >= NLOC) return;
    z2  += (size_t)slice * NLOC * HH;
    es2 += (size_t)slice * NLOC;
    ed2 += (size_t)slice * NLOC;
    const float* xp = dyn + (size_t)n * (TT * INDIM) + (size_t)(2 * q) * INDIM;
    float x0[INDIM], x1[INDIM];
    #pragma unroll
    for (int i = 0; i < INDIM; ++i) { x0[i] = xp[i]; x1[i] = xp[INDIM + i]; }
    float es0 = 0.f, es1 = 0.f, ed0 = sab, ed1 = sab;
    #pragma unroll
    for (int k = 0; k < HH; ++k) {
        float a0 = sb[k], a1 = sb[k];
        #pragma unroll
        for (int i = 0; i < INDIM; ++i) {
            a0 = fmaf(x0[i], sW[k * INDIM + i], a0);
            a1 = fmaf(x1[i], sW[k * INDIM + i], a1);
        }
        z2[(size_t)n * HH + k] = __floats2half2_rn(a0, a1);
        es0 = fmaf(saW[k], a0, es0);       es1 = fmaf(saW[k], a1, es1);
        ed0 = fmaf(saW[HH + k], a0, ed0);  ed1 = fmaf(saW[HH + k], a1, ed1);
    }
    es2[n] = make_float2(es0, es1);
    ed2[n] = make_float2(ed0, ed1);
}

// ---------------- layer-2 node transform: reads interleaved c2, writes interleaved z2
__global__ void node2_kernel(const __half2* __restrict__ c2,
                             const float* __restrict__ W, const float* __restrict__ b,
                             const float* __restrict__ aW, const float* __restrict__ ab,
                             __half2* __restrict__ z2, float2* __restrict__ es2,
                             float2* __restrict__ ed2, int nblk, int half, int swz, int qadd) {
    __shared__ float sW[HH * HH];
    __shared__ float sb[HH];
    __shared__ float saW[2 * HH];
    __shared__ float sab;
    int q, blk;
    bool alive = decode_bal(nblk, half, swz, qadd, q, blk);
    int slice = swz ? q : blockIdx.y;
    int tid = threadIdx.x;
    for (int i = tid; i < HH * HH; i += blockDim.x) sW[i] = W[i];
    if (tid < HH) sb[tid] = b[tid];
    if (tid < 2 * HH) saW[tid] = aW[tid];
    if (tid == 0) sab = ab[0];
    __syncthreads();
    if (!alive) return;
    int n = blk * blockDim.x + tid;
    if (n >= NLOC) return;
    c2  += (size_t)slice * NLOC * HH;
    z2  += (size_t)slice * NLOC * HH;
    es2 += (size_t)slice * NLOC;
    ed2 += (size_t)slice * NLOC;
    float x0[HH], x1[HH];
    const __half2* cp = c2 + (size_t)n * HH;
    #pragma unroll
    for (int i = 0; i < HH; ++i) {
        float2 f = __half22float2(cp[i]);
        x0[i] = f.x; x1[i] = f.y;
    }
    float es0 = 0.f, es1 = 0.f, ed0 = sab, ed1 = sab;
    #pragma unroll
    for (int k = 0; k < HH; ++k) {
        float a0 = sb[k], a1 = sb[k];
        #pragma unroll
        for (int i = 0; i < HH; ++i) {
            a0 = fmaf(x0[i], sW[k * HH + i], a0);
            a1 = fmaf(x1[i], sW[k * HH + i], a1);
        }
        z2[(size_t)n * HH + k] = __floats2half2_rn(a0, a1);
        es0 = fmaf(saW[k], a0, es0);       es1 = fmaf(saW[k], a1, es1);
        ed0 = fmaf(saW[HH + k], a0, ed0);  ed1 = fmaf(saW[HH + k], a1, ed1);
    }
    es2[n] = make_float2(es0, es1);
    ed2[n] = make_float2(ed0, ed1);
}

#define EDGE_FMA(wx, wy, zl)                                             \
    {                                                                    \
        float2 f0 = __half22float2(*(const __half2*)&(zl).x);            \
        float2 f1 = __half22float2(*(const __half2*)&(zl).y);            \
        float2 f2 = __half22float2(*(const __half2*)&(zl).z);            \
        float2 f3 = __half22float2(*(const __half2*)&(zl).w);            \
        den0 += (wx); den1 += (wy);                                      \
        ac0.x = fmaf((wx), f0.x, ac0.x); ac0.y = fmaf((wy), f0.y, ac0.y);\
        ac1.x = fmaf((wx), f1.x, ac1.x); ac1.y = fmaf((wy), f1.y, ac1.y);\
        ac2.x = fmaf((wx), f2.x, ac2.x); ac2.y = fmaf((wy), f2.y, ac2.y);\
        ac3.x = fmaf((wx), f3.x, ac3.x); ac3.y = fmaf((wy), f3.y, ac3.y);\
    }

// ---------------- aggregation for a t-pair: high-concurrency version.
// Lane r owns edges r*8..r*8+7 (contiguous in LDS): one ds_read_b128 gets 4
// offsets, 4 uint4 z-line loads issue back-to-back, weights re-read after.
// launch_bounds(256,8) caps VGPR at 64 -> 8 waves/SIMD; concurrency = waves x 4.
template<bool WRITE_C, bool POOL>
__global__ void __launch_bounds__(256, 8)
agg_kernel(const int* __restrict__ row_ptr, const u16* __restrict__ csr,
           const __half2* __restrict__ z2t, const float2* __restrict__ es2,
           const float2* __restrict__ ed2, __half2* __restrict__ c2out,
           unsigned int* __restrict__ pooled_u, int nblk, int half, int swz, int qadd) {
    __shared__ int    soff[4][64];
    __shared__ float2 swt[4][64];
    __shared__ float  sred[4][2][HH];
    int q, dblk;
    bool alive = decode_bal(nblk, half, swz, qadd, q, dblk);
    int slice = swz ? q : blockIdx.y;
    int lane = threadIdx.x & 63;
    int w    = threadIdx.x >> 6;
    int r    = lane >> 3;     // edge-chunk row: owns edges r*8 .. r*8+7
    int cg   = lane & 7;      // dim-group: dims cg*4 .. cg*4+3
    int d = dblk * 4 + w;
    const __half2* z2q  = z2t + (size_t)slice * NLOC * HH;
    const float2*  es2q = es2 + (size_t)slice * NLOC;
    const float2*  ed2q = ed2 + (size_t)slice * NLOC;

    float v00 = -FLT_MAX, v01 = -FLT_MAX, v10 = -FLT_MAX, v11 = -FLT_MAX;
    float v20 = -FLT_MAX, v21 = -FLT_MAX, v30 = -FLT_MAX, v31 = -FLT_MAX;

    if (alive) {
        int beg = 0, end = 0;
        float edd0 = 0.f, edd1 = 0.f;
        if (d < NLOC) {
            beg = row_ptr[d];
            end = row_ptr[d + 1];
            float2 ev = ed2q[d];
            edd0 = ev.x; edd1 = ev.y;
        }
        int deg = end - beg;
        // preload: coalesced u16 idx + ONE float2 es gather serving both t
        int il = beg + lane;
        bool valid = (il < end);
        int idx_l = valid ? (int)csr[il] : 0;
        float2 esv = es2q[idx_l];
        float e0 = esv.x + edd0; e0 = fmaxf(e0, 0.01f * e0);
        float e1 = esv.y + edd1; e1 = fmaxf(e1, 0.01f * e1);
        soff[w][lane] = idx_l << 7;              // byte offset: 128B per node
        swt[w][lane]  = make_float2(valid ? __expf(e0) : 0.f,
                                    valid ? __expf(e1) : 0.f);
        // wave-private LDS: no block barrier

        const char* zb = (const char*)z2q + cg * 16;
        float2 ac0 = {0.f, 0.f}, ac1 = {0.f, 0.f}, ac2 = {0.f, 0.f}, ac3 = {0.f, 0.f};
        float den0 = 0.f, den1 = 0.f;
        #pragma unroll
        for (int b = 0; b < 2; ++b) {
            int4 offs = *(const int4*)&soff[w][r * 8 + b * 4];
            uint4 zl0 = *(const uint4*)(zb + offs.x);
            uint4 zl1 = *(const uint4*)(zb + offs.y);
            uint4 zl2 = *(const uint4*)(zb + offs.z);
            uint4 zl3 = *(const uint4*)(zb + offs.w);
            float4 wA = *(const float4*)&swt[w][r * 8 + b * 4];      // edges 0,1
            float4 wB = *(const float4*)&swt[w][r * 8 + b * 4 + 2];  // edges 2,3
            EDGE_FMA(wA.x, wA.y, zl0);
            EDGE_FMA(wA.z, wA.w, zl1);
            EDGE_FMA(wB.x, wB.y, zl2);
            EDGE_FMA(wB.z, wB.w, zl3);
        }
        // tail for deg > 64 (not taken on this graph; correctness only)
        for (int e = 64 + r; e < deg; e += 8) {
            int s2 = (int)csr[beg + e];
            float2 esv2 = es2q[s2];
            float t0 = esv2.x + edd0; t0 = fmaxf(t0, 0.01f * t0);
            float t1 = esv2.y + edd1; t1 = fmaxf(t1, 0.01f * t1);
            float x0 = __expf(t0), x1 = __expf(t1);
            uint4 u = *(const uint4*)(zb + ((size_t)s2 << 7));
            EDGE_FMA(x0, x1, u);
        }
        // fold edge-chunk rows (strides 8,16,32)
        #pragma unroll
        for (int o = 8; o <= 32; o <<= 1) {
            ac0.x += __shfl_xor(ac0.x, o, 64); ac0.y += __shfl_xor(ac0.y, o, 64);
            ac1.x += __shfl_xor(ac1.x, o, 64); ac1.y += __shfl_xor(ac1.y, o, 64);
            ac2.x += __shfl_xor(ac2.x, o, 64); ac2.y += __shfl_xor(ac2.y, o, 64);
            ac3.x += __shfl_xor(ac3.x, o, 64); ac3.y += __shfl_xor(ac3.y, o, 64);
            den0  += __shfl_xor(den0,  o, 64); den1  += __shfl_xor(den1,  o, 64);
        }

        if (d < NLOC) {
            float r0 = 1.f / den0, r1 = 1.f / den1;
            v00 = ac0.x * r0; v00 = fmaxf(v00, __expf(fminf(v00, 0.f)) - 1.f);
            v01 = ac0.y * r1; v01 = fmaxf(v01, __expf(fminf(v01, 0.f)) - 1.f);
            v10 = ac1.x * r0; v10 = fmaxf(v10, __expf(fminf(v10, 0.f)) - 1.f);
            v11 = ac1.y * r1; v11 = fmaxf(v11, __expf(fminf(v11, 0.f)) - 1.f);
            v20 = ac2.x * r0; v20 = fmaxf(v20, __expf(fminf(v20, 0.f)) - 1.f);
            v21 = ac2.y * r1; v21 = fmaxf(v21, __expf(fminf(v21, 0.f)) - 1.f);
            v30 = ac3.x * r0; v30 = fmaxf(v30, __expf(fminf(v30, 0.f)) - 1.f);
            v31 = ac3.y * r1; v31 = fmaxf(v31, __expf(fminf(v31, 0.f)) - 1.f);
            if (WRITE_C && r == 0) {
                uint4 pk;
                __half2 h0 = __floats2half2_rn(v00, v01);
                __half2 h1 = __floats2half2_rn(v10, v11);
                __half2 h2 = __floats2half2_rn(v20, v21);
                __half2 h3 = __floats2half2_rn(v30, v31);
                pk.x = *(unsigned int*)&h0; pk.y = *(unsigned int*)&h1;
                pk.z = *(unsigned int*)&h2; pk.w = *(unsigned int*)&h3;
                *(uint4*)((char*)(c2out + (size_t)slice * NLOC * HH + (size_t)d * HH) + cg * 16) = pk;
            }
        }
    }
    if (POOL) {
        if (alive && r == 0) {
            sred[w][0][cg * 4 + 0] = v00; sred[w][1][cg * 4 + 0] = v01;
            sred[w][0][cg * 4 + 1] = v10; sred[w][1][cg * 4 + 1] = v11;
            sred[w][0][cg * 4 + 2] = v20; sred[w][1][cg * 4 + 2] = v21;
            sred[w][0][cg * 4 + 3] = v30; sred[w][1][cg * 4 + 3] = v31;
        }
        __syncthreads();
        if (alive && threadIdx.x < 64) {
            int pp = threadIdx.x >> 5;
            int dim = threadIdx.x & 31;
            float m = fmaxf(fmaxf(sred[0][pp][dim], sred[1][pp][dim]),
                            fmaxf(sred[2][pp][dim], sred[3][pp][dim]));
            atomicMax(&pooled_u[(size_t)((2 * q + pp) * HH + dim) * PSTR], fkey(m));
        }
    }
}

// ---------------- GRU over all 24 steps + heads, single block
__global__ void gru_all_kernel(const unsigned int* __restrict__ pooled_u,
                               const float* __restrict__ Wih, const float* __restrict__ Whh,
                               const float* __restrict__ bih, const float* __restrict__ bhh,
                               const float* __restrict__ WI, const float* __restrict__ bI,
                               const float* __restrict__ WR, const float* __restrict__ bR,
                               const float* __restrict__ Ws, const float* __restrict__ bs,
                               const float* __restrict__ cIv, const float* __restrict__ cRv,
                               const float* __restrict__ h0, float* __restrict__ abArr,
                               float* __restrict__ out_newI, float* __restrict__ out_newR,
                               float* __restrict__ h_fin) {
    __shared__ float pooled[HH], hs[HH], gi[96], gh[96], hc[34];
    int tid = threadIdx.x;
    float wih_r[HH], whh_r[HH];
    if (tid < 96) {
        #pragma unroll
        for (int k = 0; k < HH; ++k) {
            wih_r[k] = Wih[tid * HH + k];
            whh_r[k] = Whh[tid * HH + k];
        }
    }
    if (tid < HH) hs[tid] = h0[tid];
    __syncthreads();
    for (int t = 0; t < TT; ++t) {
        if (tid < HH) pooled[tid] = funkey(pooled_u[(size_t)(t * HH + tid) * PSTR]);
        __syncthreads();
        if (tid < 96) {
            float a = bih[tid], g = bhh[tid];
            #pragma unroll
            for (int k = 0; k < HH; ++k) {
                a = fmaf(wih_r[k], pooled[k], a);
                g = fmaf(whh_r[k], hs[k], g);
            }
            gi[tid] = a; gh[tid] = g;
        }
        __syncthreads();
        if (tid < HH) {
            float r  = 1.f / (1.f + expf(-(gi[tid] + gh[tid])));
            float zg = 1.f / (1.f + expf(-(gi[HH + tid] + gh[HH + tid])));
            float nn = tanhf(gi[2 * HH + tid] + r * gh[2 * HH + tid]);
            float hn = (1.f - zg) * nn + zg * hs[tid];
            hs[tid] = hn;
            hc[tid] = hn;
        }
        if (tid == 32) hc[32] = cIv[t];
        if (tid == 33) hc[33] = cRv[t];
        __syncthreads();
        if (tid < PWN) {
            float a = bI[tid];
            #pragma unroll
            for (int k = 0; k < 34; ++k) a = fmaf(WI[tid * 34 + k], hc[k], a);
            out_newI[t * PWN + tid] = a;
        } else if (tid >= 32 && tid < 32 + PWN) {
            int p = tid - 32;
            float a = bR[p];
            #pragma unroll
            for (int k = 0; k < 34; ++k) a = fmaf(WR[p * 34 + k], hc[k], a);
            out_newR[t * PWN + p] = a;
        } else if (tid == 64 || tid == 65) {
            int p = tid - 64;
            float a = bs[p];
            #pragma unroll
            for (int k = 0; k < 34; ++k) a = fmaf(Ws[p * 34 + k], hc[k], a);
            abArr[2 * t + p] = 1.f / (1.f + expf(-a));
        }
        __syncthreads();
    }
    if (tid < HH) h_fin[tid] = hs[tid];
}

// ---------------- SIR rollout for all (n, t)
__global__ void sir_kernel(const float* __restrict__ Nin, const float* __restrict__ Iv,
                           const float* __restrict__ Rv, const float* __restrict__ abArr,
                           float* __restrict__ phyI, float* __restrict__ phyR) {
    int idx = blockIdx.x * blockDim.x + threadIdx.x; // n*TT + t
    if (idx >= NLOC * TT) return;
    int n = idx / TT, t = idx - n * TT;
    float Nv = Nin[n];
    float alpha = abArr[2 * t], beta = abArr[2 * t + 1];
    float lI = Iv[t], lR = Rv[t];
    float* oI = phyI + (size_t)idx * PWN;
    float* oR = phyR + (size_t)idx * PWN;
    #pragma unroll
    for (int p = 0; p < PWN; ++p) {
        float lS = Nv - lI - lR;
        float dI = alpha * lI * (lS / Nv) - beta * lI;
        float dR = beta * lI;
        oI[p] = dI;
        oR[p] = dR;
        lI += dI;
        lR += dR;
    }
}

extern "C" void kernel_launch(void* const* d_in, const int* in_sizes, int n_in,
                              void* d_out, int out_size, void* d_ws, size_t ws_size,
                              hipStream_t stream) {
    const float* dynamic = (const float*)d_in[0];
    const float* cIv = (const float*)d_in[1];
    const float* cRv = (const float*)d_in[2];
    const float* Nin = (const float*)d_in[3];
    const float* Iv  = (const float*)d_in[4];
    const float* Rv  = (const float*)d_in[5];
    const float* h0  = (const float*)d_in[6];
    const float* W1  = (const float*)d_in[7];
    const float* b1  = (const float*)d_in[8];
    const float* aW1 = (const float*)d_in[9];
    const float* ab1 = (const float*)d_in[10];
    const float* W2  = (const float*)d_in[11];
    const float* b2  = (const float*)d_in[12];
    const float* aW2 = (const float*)d_in[13];
    const float* ab2 = (const float*)d_in[14];
    const float* Wih = (const float*)d_in[15];
    const float* Whh = (const float*)d_in[16];
    const float* bih = (const float*)d_in[17];
    const float* bhh = (const float*)d_in[18];
    const float* WI  = (const float*)d_in[19];
    const float* bI  = (const float*)d_in[20];
    const float* WR  = (const float*)d_in[21];
    const float* bR  = (const float*)d_in[22];
    const float* Ws  = (const float*)d_in[23];
    const float* bs  = (const float*)d_in[24];
    const int* esrc  = (const int*)d_in[25];
    const int* edst  = (const int*)d_in[26];
    const int E = in_sizes[25];

    float* out = (float*)d_out;
    float* out_newI = out;                         // (1,24,15)
    float* out_newR = out + TT * PWN;              // (1,24,15)
    float* phyI = out + 2 * TT * PWN;              // (20000,24,15)
    float* phyR = phyI + (size_t)NLOC * TT * PWN;
    float* h_fin = phyR + (size_t)NLOC * TT * PWN; // (1,32)

    // ---------------- workspace layout ----------------
    char* p = (char*)d_ws;
    int* cnt = (int*)p;                 p += (size_t)NLOC * 4;
    int* fill = (int*)p;                p += (size_t)NLOC * 4;
    int* row_ptr = (int*)p;             p += (size_t)(NLOC + 2) * 4;
    u16* csr = (u16*)p;                 p += ((size_t)E * 2 + 15) & ~(size_t)15;
    unsigned int* pooled_u = (unsigned int*)p; p += (size_t)TT * HH * PSTR * 4;
    float* abArr = (float*)p;           p += (size_t)2 * TT * 4;
    p = (char*)(((size_t)p + 127) & ~(size_t)127);
    size_t fixed_bytes = (size_t)(p - (char*)d_ws);
    size_t per_q_bytes = (size_t)NLOC * HH * 4 * 2 + (size_t)NLOC * 8 * 2;
    int B = 1;
    if (ws_size > fixed_bytes + per_q_bytes)
        B = (int)((ws_size - fixed_bytes) / per_q_bytes);
    if (B > NP) B = NP;
    if (B < 1) B = 1;
    __half2* zb  = (__half2*)p;
    __half2* cb  = zb + (size_t)B * NLOC * HH;
    float2* es2  = (float2*)(cb + (size_t)B * NLOC * HH);
    float2* ed2  = es2 + (size_t)B * NLOC;

    hipMemsetAsync(cnt, 0, (size_t)2 * NLOC * 4, stream);
    hipMemsetAsync(pooled_u, 0, (size_t)TT * HH * PSTR * 4, stream);

    int egrid = (E + 255) / 256;
    count_kernel<<<egrid, 256, 0, stream>>>(edst, cnt, E);
    scan_kernel<<<1, 1024, 0, stream>>>(cnt, row_ptr, NLOC);
    scatter_kernel<<<egrid, 256, 0, stream>>>(esrc, edst, row_ptr, fill, csr, E);

    const int NBLK_N = (NLOC + 255) / 256;   // 79
    const int NBLK_A = (NLOC + 3) / 4;       // 5000
    const int HALF_N = (NBLK_N + 1) / 2;     // 40
    const int HALF_A = (NBLK_A + 1) / 2;     // 2500

    if (B >= NP) {
        // full batch: balanced-XCD flat grids (each XCD: 1 full pair + half pair)
        dim3 ng(8 * (NBLK_N + HALF_N)), ag(8 * (NBLK_A + HALF_A));
        node1_kernel<<<ng, 256, 0, stream>>>(dynamic, W1, b1, aW1, ab1,
                                             zb, es2, ed2, NBLK_N, HALF_N, 1, 0);
        agg_kernel<true, false><<<ag, 256, 0, stream>>>(
            row_ptr, csr, zb, es2, ed2, cb, pooled_u, NBLK_A, HALF_A, 1, 0);
        node2_kernel<<<ng, 256, 0, stream>>>(cb, W2, b2, aW2, ab2,
                                             zb, es2, ed2, NBLK_N, HALF_N, 1, 0);
        agg_kernel<false, true><<<ag, 256, 0, stream>>>(
            row_ptr, csr, zb, es2, ed2, nullptr, pooled_u, NBLK_A, HALF_A, 1, 0);
    } else {
        for (int qbase = 0; qbase < NP; qbase += B) {
            int Bc = NP - qbase; if (Bc > B) Bc = B;
            dim3 ng(NBLK_N, Bc), ag(NBLK_A, Bc);
            node1_kernel<<<ng, 256, 0, stream>>>(dynamic, W1, b1, aW1, ab1,
                                                 zb, es2, ed2, NBLK_N, HALF_N, 0, qbase);
            agg_kernel<true, false><<<ag, 256, 0, stream>>>(
                row_ptr, csr, zb, es2, ed2, cb, pooled_u, NBLK_A, HALF_A, 0, qbase);
            node2_kernel<<<ng, 256, 0, stream>>>(cb, W2, b2, aW2, ab2,
                                                 zb, es2, ed2, NBLK_N, HALF_N, 0, qbase);
            agg_kernel<false, true><<<ag, 256, 0, stream>>>(
                row_ptr, csr, zb, es2, ed2, nullptr, pooled_u, NBLK_A, HALF_A, 0, qbase);
        }
    }

    gru_all_kernel<<<1, 128, 0, stream>>>(pooled_u, Wih, Whh, bih, bhh,
                                          WI, bI, WR, bR, Ws, bs, cIv, cRv,
                                          h0, abArr, out_newI, out_newR, h_fin);
    sir_kernel<<<(NLOC * TT + 255) / 256, 256, 0, stream>>>(Nin, Iv, Rv, abArr, phyI, phyR);
}

// Round 13
// 625.297 us; speedup vs baseline: 1.1877x; 1.1877x over previous
//
#include <hip/hip_runtime.h>
#include <hip/hip_fp16.h>
#include <math.h>
#include <float.h>

#define NLOC 20000
#define TT   24
#define NP   12      // timestep pairs
#define INDIM 18
#define HH   32
#define PWN  15
#define PSTR 32      // uint stride between pooled keys (128B)

typedef unsigned short u16;

__device__ __forceinline__ unsigned int fkey(float f) {
    unsigned int b = __float_as_uint(f);
    return b ^ ((unsigned int)((int)b >> 31) | 0x80000000u);
}
__device__ __forceinline__ float funkey(unsigned int u) {
    return (u & 0x80000000u) ? __uint_as_float(u ^ 0x80000000u) : __uint_as_float(~u);
}

// Balanced pair->XCD map: XCD x owns pair x (all nblk blocks) plus half of pair
// 8+(x>>1) -> 1.5 pairs per XCD (vs 2 for naive q%8). blockIdx%8 ~ XCD.
__device__ __forceinline__ bool decode_bal(int nblk, int half, int swz, int qadd,
                                           int& q, int& blk) {
    if (swz) {
        int F = blockIdx.x;
        int x = F & 7;
        int g = F >> 3;
        if (g < nblk) { q = x; blk = g; return true; }
        int h = g - nblk;                    // [0, half)
        q = 8 + (x >> 1);
        blk = (x & 1) * half + h;
        return blk < nblk;
    }
    q = qadd + blockIdx.y;
    blk = blockIdx.x;
    return true;
}

// ---------------- CSR build ----------------
__global__ void count_kernel(const int* __restrict__ dst, int* __restrict__ cnt, int E) {
    int e = blockIdx.x * blockDim.x + threadIdx.x;
    if (e < E) atomicAdd(&cnt[dst[e]], 1);
}

__global__ void scan_kernel(const int* __restrict__ cnt, int* __restrict__ row_ptr, int n) {
    __shared__ int sums[1024];
    const int CH = 20;
    int tid = threadIdx.x;
    int base = tid * CH;
    int local[CH];
    int s = 0;
    #pragma unroll
    for (int i = 0; i < CH; ++i) {
        int idx = base + i;
        int v = (idx < n) ? cnt[idx] : 0;
        local[i] = s;
        s += v;
    }
    sums[tid] = s;
    __syncthreads();
    for (int o = 1; o < 1024; o <<= 1) {
        int v = (tid >= o) ? sums[tid - o] : 0;
        __syncthreads();
        sums[tid] += v;
        __syncthreads();
    }
    int pre = (tid > 0) ? sums[tid - 1] : 0;
    #pragma unroll
    for (int i = 0; i < CH; ++i) {
        int idx = base + i;
        if (idx < n) row_ptr[idx] = pre + local[i];
    }
    if (tid == 1023) row_ptr[n] = sums[1023];
}

__global__ void scatter_kernel(const int* __restrict__ src, const int* __restrict__ dst,
                               const int* __restrict__ row_ptr, int* __restrict__ fill,
                               u16* __restrict__ csr_src, int E) {
    int e = blockIdx.x * blockDim.x + threadIdx.x;
    if (e < E) {
        int d = dst[e];
        int pos = row_ptr[d] + atomicAdd(&fill[d], 1);
        csr_src[pos] = (u16)src[e];
    }
}

// ---------------- layer-1 node transform for a t-pair: z2 interleaved half2(t0,t1)
__global__ void node1_kernel(const float* __restrict__ dyn,
                             const float* __restrict__ W, const float* __restrict__ b,
                             const float* __restrict__ aW, const float* __restrict__ ab,
                             __half2* __restrict__ z2, float2* __restrict__ es2,
                             float2* __restrict__ ed2, int nblk, int half, int swz, int qadd) {
    int q, blk;
    if (!decode_bal(nblk, half, swz, qadd, q, blk)) return;   // block-uniform
    __shared__ float sW[HH * INDIM];
    __shared__ float sb[HH];
    __shared__ float saW[2 * HH];
    __shared__ float sab;
    int slice = swz ? q : blockIdx.y;
    int tid = threadIdx.x;
    for (int i = tid; i < HH * INDIM; i += blockDim.x) sW[i] = W[i];
    if (tid < HH) sb[tid] = b[tid];
    if (tid < 2 * HH) saW[tid] = aW[tid];
    if (tid == 0) sab = ab[0];
    __syncthreads();
    int n = blk * blockDim.x + tid;
    if (n >= NLOC) return;
    z2  += (size_t)slice * NLOC * HH;
    es2 += (size_t)slice * NLOC;
    ed2 += (size_t)slice * NLOC;
    const float* xp = dyn + (size_t)n * (TT * INDIM) + (size_t)(2 * q) * INDIM;
    float x0[INDIM], x1[INDIM];
    #pragma unroll
    for (int i = 0; i < INDIM; ++i) { x0[i] = xp[i]; x1[i] = xp[INDIM + i]; }
    float es0 = 0.f, es1 = 0.f, ed0 = sab, ed1 = sab;
    #pragma unroll
    for (int k = 0; k < HH; ++k) {
        float a0 = sb[k], a1 = sb[k];
        #pragma unroll
        for (int i = 0; i < INDIM; ++i) {
            a0 = fmaf(x0[i], sW[k * INDIM + i], a0);
            a1 = fmaf(x1[i], sW[k * INDIM + i], a1);
        }
        z2[(size_t)n * HH + k] = __floats2half2_rn(a0, a1);
        es0 = fmaf(saW[k], a0, es0);       es1 = fmaf(saW[k], a1, es1);
        ed0 = fmaf(saW[HH + k], a0, ed0);  ed1 = fmaf(saW[HH + k], a1, ed1);
    }
    es2[n] = make_float2(es0, es1);
    ed2[n] = make_float2(ed0, ed1);
}

// ---------------- layer-2 node transform: reads interleaved c2, writes interleaved z2
__global__ void node2_kernel(const __half2* __restrict__ c2,
                             const float* __restrict__ W, const float* __restrict__ b,
                             const float* __restrict__ aW, const float* __restrict__ ab,
                             __half2* __restrict__ z2, float2* __restrict__ es2,
                             float2* __restrict__ ed2, int nblk, int half, int swz, int qadd) {
    int q, blk;
    if (!decode_bal(nblk, half, swz, qadd, q, blk)) return;   // block-uniform
    __shared__ float sW[HH * HH];
    __shared__ float sb[HH];
    __shared__ float saW[2 * HH];
    __shared__ float sab;
    int slice = swz ? q : blockIdx.y;
    int tid = threadIdx.x;
    for (int i = tid; i < HH * HH; i += blockDim.x) sW[i] = W[i];
    if (tid < HH) sb[tid] = b[tid];
    if (tid < 2 * HH) saW[tid] = aW[tid];
    if (tid == 0) sab = ab[0];
    __syncthreads();
    int n = blk * blockDim.x + tid;
    if (n >= NLOC) return;
    c2  += (size_t)slice * NLOC * HH;
    z2  += (size_t)slice * NLOC * HH;
    es2 += (size_t)slice * NLOC;
    ed2 += (size_t)slice * NLOC;
    float x0[HH], x1[HH];
    const __half2* cp = c2 + (size_t)n * HH;
    #pragma unroll
    for (int i = 0; i < HH; ++i) {
        float2 f = __half22float2(cp[i]);
        x0[i] = f.x; x1[i] = f.y;
    }
    float es0 = 0.f, es1 = 0.f, ed0 = sab, ed1 = sab;
    #pragma unroll
    for (int k = 0; k < HH; ++k) {
        float a0 = sb[k], a1 = sb[k];
        #pragma unroll
        for (int i = 0; i < HH; ++i) {
            a0 = fmaf(x0[i], sW[k * HH + i], a0);
            a1 = fmaf(x1[i], sW[k * HH + i], a1);
        }
        z2[(size_t)n * HH + k] = __floats2half2_rn(a0, a1);
        es0 = fmaf(saW[k], a0, es0);       es1 = fmaf(saW[k], a1, es1);
        ed0 = fmaf(saW[HH + k], a0, ed0);  ed1 = fmaf(saW[HH + k], a1, ed1);
    }
    es2[n] = make_float2(es0, es1);
    ed2[n] = make_float2(ed0, ed1);
}

// ---------------- aggregation for a t-pair (proven 265us body, balanced map):
// wave = 8 edge-rows x 8 dim-groups; lane loads dwordx4 (4 dims x half2(t0,t1));
// one 128B z-line per edge serves BOTH timesteps. LB(256,4); no block barrier
// before the loop (wave-private LDS staging).
template<bool WRITE_C, bool POOL>
__global__ void __launch_bounds__(256, 4)
agg_kernel(const int* __restrict__ row_ptr, const u16* __restrict__ csr,
           const __half2* __restrict__ z2t, const float2* __restrict__ es2,
           const float2* __restrict__ ed2, __half2* __restrict__ c2out,
           unsigned int* __restrict__ pooled_u, int nblk, int half, int swz, int qadd) {
    int q, dblk;
    if (!decode_bal(nblk, half, swz, qadd, q, dblk)) return;  // block-uniform
    __shared__ int    soff[4][64];
    __shared__ float2 swt[4][64];
    __shared__ float  sred[4][2][HH];
    int slice = swz ? q : blockIdx.y;
    int lane = threadIdx.x & 63;
    int w    = threadIdx.x >> 6;
    int r    = lane >> 3;     // edge-row 0..7
    int cg   = lane & 7;      // dim-group: dims cg*4 .. cg*4+3
    int d = dblk * 4 + w;
    const __half2* z2q  = z2t + (size_t)slice * NLOC * HH;
    const float2*  es2q = es2 + (size_t)slice * NLOC;
    const float2*  ed2q = ed2 + (size_t)slice * NLOC;

    int beg = 0, end = 0;
    float edd0 = 0.f, edd1 = 0.f;
    if (d < NLOC) {
        beg = row_ptr[d];
        end = row_ptr[d + 1];
        float2 ev = ed2q[d];
        edd0 = ev.x; edd1 = ev.y;
    }
    int deg = end - beg;
    // preload: coalesced u16 idx + ONE float2 es gather serving both t
    int il = beg + lane;
    bool valid = (il < end);
    int idx_l = valid ? (int)csr[il] : 0;
    float2 esv = es2q[idx_l];
    float e0 = esv.x + edd0; e0 = fmaxf(e0, 0.01f * e0);
    float e1 = esv.y + edd1; e1 = fmaxf(e1, 0.01f * e1);
    float w0 = valid ? __expf(e0) : 0.f;
    float w1 = valid ? __expf(e1) : 0.f;
    soff[w][lane] = idx_l << 7;                 // byte offset: 128B per node
    swt[w][lane]  = make_float2(w0, w1);
    // wave-private LDS: no block barrier

    const char* zb = (const char*)z2q + cg * 16;
    float2 ac0 = {0.f, 0.f}, ac1 = {0.f, 0.f}, ac2 = {0.f, 0.f}, ac3 = {0.f, 0.f};
    float den0 = 0.f, den1 = 0.f;
    #pragma unroll
    for (int pass = 0; pass < 8; ++pass) {
        int    off = soff[w][pass * 8 + r];
        float2 wv  = swt[w][pass * 8 + r];
        uint4 u = *(const uint4*)(zb + off);    // 4 dims x half2(t0,t1)
        den0 += wv.x; den1 += wv.y;
        float2 f0 = __half22float2(*(const __half2*)&u.x);
        float2 f1 = __half22float2(*(const __half2*)&u.y);
        float2 f2 = __half22float2(*(const __half2*)&u.z);
        float2 f3 = __half22float2(*(const __half2*)&u.w);
        ac0.x = fmaf(wv.x, f0.x, ac0.x); ac0.y = fmaf(wv.y, f0.y, ac0.y);
        ac1.x = fmaf(wv.x, f1.x, ac1.x); ac1.y = fmaf(wv.y, f1.y, ac1.y);
        ac2.x = fmaf(wv.x, f2.x, ac2.x); ac2.y = fmaf(wv.y, f2.y, ac2.y);
        ac3.x = fmaf(wv.x, f3.x, ac3.x); ac3.y = fmaf(wv.y, f3.y, ac3.y);
    }
    // tail for deg > 64 (not taken on this graph; correctness only)
    for (int e = 64 + r; e < deg; e += 8) {
        int s2 = (int)csr[beg + e];
        float2 esv2 = es2q[s2];
        float t0 = esv2.x + edd0; t0 = fmaxf(t0, 0.01f * t0);
        float t1 = esv2.y + edd1; t1 = fmaxf(t1, 0.01f * t1);
        float x0 = __expf(t0), x1 = __expf(t1);
        den0 += x0; den1 += x1;
        uint4 u = *(const uint4*)(zb + ((size_t)s2 << 7));
        float2 f0 = __half22float2(*(const __half2*)&u.x);
        float2 f1 = __half22float2(*(const __half2*)&u.y);
        float2 f2 = __half22float2(*(const __half2*)&u.z);
        float2 f3 = __half22float2(*(const __half2*)&u.w);
        ac0.x = fmaf(x0, f0.x, ac0.x); ac0.y = fmaf(x1, f0.y, ac0.y);
        ac1.x = fmaf(x0, f1.x, ac1.x); ac1.y = fmaf(x1, f1.y, ac1.y);
        ac2.x = fmaf(x0, f2.x, ac2.x); ac2.y = fmaf(x1, f2.y, ac2.y);
        ac3.x = fmaf(x0, f3.x, ac3.x); ac3.y = fmaf(x1, f3.y, ac3.y);
    }
    // fold edge-rows (strides 8,16,32)
    #pragma unroll
    for (int o = 8; o <= 32; o <<= 1) {
        ac0.x += __shfl_xor(ac0.x, o, 64); ac0.y += __shfl_xor(ac0.y, o, 64);
        ac1.x += __shfl_xor(ac1.x, o, 64); ac1.y += __shfl_xor(ac1.y, o, 64);
        ac2.x += __shfl_xor(ac2.x, o, 64); ac2.y += __shfl_xor(ac2.y, o, 64);
        ac3.x += __shfl_xor(ac3.x, o, 64); ac3.y += __shfl_xor(ac3.y, o, 64);
        den0  += __shfl_xor(den0,  o, 64); den1  += __shfl_xor(den1,  o, 64);
    }

    float v00 = -FLT_MAX, v01 = -FLT_MAX, v10 = -FLT_MAX, v11 = -FLT_MAX;
    float v20 = -FLT_MAX, v21 = -FLT_MAX, v30 = -FLT_MAX, v31 = -FLT_MAX;
    if (d < NLOC) {
        float r0 = 1.f / den0, r1 = 1.f / den1;
        // branchless elu: max(x, exp(min(x,0))-1)
        v00 = ac0.x * r0; v00 = fmaxf(v00, __expf(fminf(v00, 0.f)) - 1.f);
        v01 = ac0.y * r1; v01 = fmaxf(v01, __expf(fminf(v01, 0.f)) - 1.f);
        v10 = ac1.x * r0; v10 = fmaxf(v10, __expf(fminf(v10, 0.f)) - 1.f);
        v11 = ac1.y * r1; v11 = fmaxf(v11, __expf(fminf(v11, 0.f)) - 1.f);
        v20 = ac2.x * r0; v20 = fmaxf(v20, __expf(fminf(v20, 0.f)) - 1.f);
        v21 = ac2.y * r1; v21 = fmaxf(v21, __expf(fminf(v21, 0.f)) - 1.f);
        v30 = ac3.x * r0; v30 = fmaxf(v30, __expf(fminf(v30, 0.f)) - 1.f);
        v31 = ac3.y * r1; v31 = fmaxf(v31, __expf(fminf(v31, 0.f)) - 1.f);
        if (WRITE_C && r == 0) {
            uint4 pk;
            __half2 h0 = __floats2half2_rn(v00, v01);
            __half2 h1 = __floats2half2_rn(v10, v11);
            __half2 h2 = __floats2half2_rn(v20, v21);
            __half2 h3 = __floats2half2_rn(v30, v31);
            pk.x = *(unsigned int*)&h0; pk.y = *(unsigned int*)&h1;
            pk.z = *(unsigned int*)&h2; pk.w = *(unsigned int*)&h3;
            *(uint4*)((char*)(c2out + (size_t)slice * NLOC * HH + (size_t)d * HH) + cg * 16) = pk;
        }
    }
    if (POOL) {
        if (r == 0) {
            sred[w][0][cg * 4 + 0] = v00; sred[w][1][cg * 4 + 0] = v01;
            sred[w][0][cg * 4 + 1] = v10; sred[w][1][cg * 4 + 1] = v11;
            sred[w][0][cg * 4 + 2] = v20; sred[w][1][cg * 4 + 2] = v21;
            sred[w][0][cg * 4 + 3] = v30; sred[w][1][cg * 4 + 3] = v31;
        }
        __syncthreads();
        if (threadIdx.x < 64) {
            int pp = threadIdx.x >> 5;      // t-parity
            int dim = threadIdx.x & 31;
            float m = fmaxf(fmaxf(sred[0][pp][dim], sred[1][pp][dim]),
                            fmaxf(sred[2][pp][dim], sred[3][pp][dim]));
            atomicMax(&pooled_u[(size_t)((2 * q + pp) * HH + dim) * PSTR], fkey(m));
        }
    }
}

// ---------------- GRU over all 24 steps + heads, single block
__global__ void gru_all_kernel(const unsigned int* __restrict__ pooled_u,
                               const float* __restrict__ Wih, const float* __restrict__ Whh,
                               const float* __restrict__ bih, const float* __restrict__ bhh,
                               const float* __restrict__ WI, const float* __restrict__ bI,
                               const float* __restrict__ WR, const float* __restrict__ bR,
                               const float* __restrict__ Ws, const float* __restrict__ bs,
                               const float* __restrict__ cIv, const float* __restrict__ cRv,
                               const float* __restrict__ h0, float* __restrict__ abArr,
                               float* __restrict__ out_newI, float* __restrict__ out_newR,
                               float* __restrict__ h_fin) {
    __shared__ float pooled[HH], hs[HH], gi[96], gh[96], hc[34];
    int tid = threadIdx.x;
    float wih_r[HH], whh_r[HH];
    if (tid < 96) {
        #pragma unroll
        for (int k = 0; k < HH; ++k) {
            wih_r[k] = Wih[tid * HH + k];
            whh_r[k] = Whh[tid * HH + k];
        }
    }
    if (tid < HH) hs[tid] = h0[tid];
    __syncthreads();
    for (int t = 0; t < TT; ++t) {
        if (tid < HH) pooled[tid] = funkey(pooled_u[(size_t)(t * HH + tid) * PSTR]);
        __syncthreads();
        if (tid < 96) {
            float a = bih[tid], g = bhh[tid];
            #pragma unroll
            for (int k = 0; k < HH; ++k) {
                a = fmaf(wih_r[k], pooled[k], a);
                g = fmaf(whh_r[k], hs[k], g);
            }
            gi[tid] = a; gh[tid] = g;
        }
        __syncthreads();
        if (tid < HH) {
            float r  = 1.f / (1.f + expf(-(gi[tid] + gh[tid])));
            float zg = 1.f / (1.f + expf(-(gi[HH + tid] + gh[HH + tid])));
            float nn = tanhf(gi[2 * HH + tid] + r * gh[2 * HH + tid]);
            float hn = (1.f - zg) * nn + zg * hs[tid];
            hs[tid] = hn;
            hc[tid] = hn;
        }
        if (tid == 32) hc[32] = cIv[t];
        if (tid == 33) hc[33] = cRv[t];
        __syncthreads();
        if (tid < PWN) {
            float a = bI[tid];
            #pragma unroll
            for (int k = 0; k < 34; ++k) a = fmaf(WI[tid * 34 + k], hc[k], a);
            out_newI[t * PWN + tid] = a;
        } else if (tid >= 32 && tid < 32 + PWN) {
            int p = tid - 32;
            float a = bR[p];
            #pragma unroll
            for (int k = 0; k < 34; ++k) a = fmaf(WR[p * 34 + k], hc[k], a);
            out_newR[t * PWN + p] = a;
        } else if (tid == 64 || tid == 65) {
            int p = tid - 64;
            float a = bs[p];
            #pragma unroll
            for (int k = 0; k < 34; ++k) a = fmaf(Ws[p * 34 + k], hc[k], a);
            abArr[2 * t + p] = 1.f / (1.f + expf(-a));
        }
        __syncthreads();
    }
    if (tid < HH) h_fin[tid] = hs[tid];
}

// ---------------- SIR rollout for all (n, t)
__global__ void sir_kernel(const float* __restrict__ Nin, const float* __restrict__ Iv,
                           const float* __restrict__ Rv, const float* __restrict__ abArr,
                           float* __restrict__ phyI, float* __restrict__ phyR) {
    int idx = blockIdx.x * blockDim.x + threadIdx.x; // n*TT + t
    if (idx >= NLOC * TT) return;
    int n = idx / TT, t = idx - n * TT;
    float Nv = Nin[n];
    float alpha = abArr[2 * t], beta = abArr[2 * t + 1];
    float lI = Iv[t], lR = Rv[t];
    float* oI = phyI + (size_t)idx * PWN;
    float* oR = phyR + (size_t)idx * PWN;
    #pragma unroll
    for (int p = 0; p < PWN; ++p) {
        float lS = Nv - lI - lR;
        float dI = alpha * lI * (lS / Nv) - beta * lI;
        float dR = beta * lI;
        oI[p] = dI;
        oR[p] = dR;
        lI += dI;
        lR += dR;
    }
}

extern "C" void kernel_launch(void* const* d_in, const int* in_sizes, int n_in,
                              void* d_out, int out_size, void* d_ws, size_t ws_size,
                              hipStream_t stream) {
    const float* dynamic = (const float*)d_in[0];
    const float* cIv = (const float*)d_in[1];
    const float* cRv = (const float*)d_in[2];
    const float* Nin = (const float*)d_in[3];
    const float* Iv  = (const float*)d_in[4];
    const float* Rv  = (const float*)d_in[5];
    const float* h0  = (const float*)d_in[6];
    const float* W1  = (const float*)d_in[7];
    const float* b1  = (const float*)d_in[8];
    const float* aW1 = (const float*)d_in[9];
    const float* ab1 = (const float*)d_in[10];
    const float* W2  = (const float*)d_in[11];
    const float* b2  = (const float*)d_in[12];
    const float* aW2 = (const float*)d_in[13];
    const float* ab2 = (const float*)d_in[14];
    const float* Wih = (const float*)d_in[15];
    const float* Whh = (const float*)d_in[16];
    const float* bih = (const float*)d_in[17];
    const float* bhh = (const float*)d_in[18];
    const float* WI  = (const float*)d_in[19];
    const float* bI  = (const float*)d_in[20];
    const float* WR  = (const float*)d_in[21];
    const float* bR  = (const float*)d_in[22];
    const float* Ws  = (const float*)d_in[23];
    const float* bs  = (const float*)d_in[24];
    const int* esrc  = (const int*)d_in[25];
    const int* edst  = (const int*)d_in[26];
    const int E = in_sizes[25];

    float* out = (float*)d_out;
    float* out_newI = out;                         // (1,24,15)
    float* out_newR = out + TT * PWN;              // (1,24,15)
    float* phyI = out + 2 * TT * PWN;              // (20000,24,15)
    float* phyR = phyI + (size_t)NLOC * TT * PWN;
    float* h_fin = phyR + (size_t)NLOC * TT * PWN; // (1,32)

    // ---------------- workspace layout ----------------
    char* p = (char*)d_ws;
    int* cnt = (int*)p;                 p += (size_t)NLOC * 4;
    int* fill = (int*)p;                p += (size_t)NLOC * 4;
    int* row_ptr = (int*)p;             p += (size_t)(NLOC + 2) * 4;
    u16* csr = (u16*)p;                 p += ((size_t)E * 2 + 15) & ~(size_t)15;
    unsigned int* pooled_u = (unsigned int*)p; p += (size_t)TT * HH * PSTR * 4;
    float* abArr = (float*)p;           p += (size_t)2 * TT * 4;
    p = (char*)(((size_t)p + 127) & ~(size_t)127);
    size_t fixed_bytes = (size_t)(p - (char*)d_ws);
    size_t per_q_bytes = (size_t)NLOC * HH * 4 * 2 + (size_t)NLOC * 8 * 2;
    int B = 1;
    if (ws_size > fixed_bytes + per_q_bytes)
        B = (int)((ws_size - fixed_bytes) / per_q_bytes);
    if (B > NP) B = NP;
    if (B < 1) B = 1;
    __half2* zb  = (__half2*)p;
    __half2* cb  = zb + (size_t)B * NLOC * HH;
    float2* es2  = (float2*)(cb + (size_t)B * NLOC * HH);
    float2* ed2  = es2 + (size_t)B * NLOC;

    hipMemsetAsync(cnt, 0, (size_t)2 * NLOC * 4, stream);
    hipMemsetAsync(pooled_u, 0, (size_t)TT * HH * PSTR * 4, stream);

    int egrid = (E + 255) / 256;
    count_kernel<<<egrid, 256, 0, stream>>>(edst, cnt, E);
    scan_kernel<<<1, 1024, 0, stream>>>(cnt, row_ptr, NLOC);
    scatter_kernel<<<egrid, 256, 0, stream>>>(esrc, edst, row_ptr, fill, csr, E);

    const int NBLK_N = (NLOC + 255) / 256;   // 79
    const int NBLK_A = (NLOC + 3) / 4;       // 5000
    const int HALF_N = (NBLK_N + 1) / 2;     // 40
    const int HALF_A = (NBLK_A + 1) / 2;     // 2500

    if (B >= NP) {
        // full batch: balanced-XCD flat grids (each XCD: 1 full pair + half pair)
        dim3 ng(8 * (NBLK_N + HALF_N)), ag(8 * (NBLK_A + HALF_A));
        node1_kernel<<<ng, 256, 0, stream>>>(dynamic, W1, b1, aW1, ab1,
                                             zb, es2, ed2, NBLK_N, HALF_N, 1, 0);
        agg_kernel<true, false><<<ag, 256, 0, stream>>>(
            row_ptr, csr, zb, es2, ed2, cb, pooled_u, NBLK_A, HALF_A, 1, 0);
        node2_kernel<<<ng, 256, 0, stream>>>(cb, W2, b2, aW2, ab2,
                                             zb, es2, ed2, NBLK_N, HALF_N, 1, 0);
        agg_kernel<false, true><<<ag, 256, 0, stream>>>(
            row_ptr, csr, zb, es2, ed2, nullptr, pooled_u, NBLK_A, HALF_A, 1, 0);
    } else {
        for (int qbase = 0; qbase < NP; qbase += B) {
            int Bc = NP - qbase; if (Bc > B) Bc = B;
            dim3 ng(NBLK_N, Bc), ag(NBLK_A, Bc);
            node1_kernel<<<ng, 256, 0, stream>>>(dynamic, W1, b1, aW1, ab1,
                                                 zb, es2, ed2, NBLK_N, HALF_N, 0, qbase);
            agg_kernel<true, false><<<ag, 256, 0, stream>>>(
                row_ptr, csr, zb, es2, ed2, cb, pooled_u, NBLK_A, HALF_A, 0, qbase);
            node2_kernel<<<ng, 256, 0, stream>>>(cb, W2, b2, aW2, ab2,
                                                 zb, es2, ed2, NBLK_N, HALF_N, 0, qbase);
            agg_kernel<false, true><<<ag, 256, 0, stream>>>(
                row_ptr, csr, zb, es2, ed2, nullptr, pooled_u, NBLK_A, HALF_A, 0, qbase);
        }
    }

    gru_all_kernel<<<1, 128, 0, stream>>>(pooled_u, Wih, Whh, bih, bhh,
                                          WI, bI, WR, bR, Ws, bs, cIv, cRv,
                                          h0, abArr, out_newI, out_newR, h_fin);
    sir_kernel<<<(NLOC * TT + 255) / 256, 256, 0, stream>>>(Nin, Iv, Rv, abArr, phyI, phyR);
}